// Round 2
// baseline (202.552 us; speedup 1.0000x reference)
//
#include <hip/hip_runtime.h>
#include <math.h>

#define KPOT 5
#define THREADS 256
#define CHUNK 4                                   // rows per chunk (one float4-pair)
#define NCHUNK 2                                  // prefetched chunks per thread
#define RPT (CHUNK * NCHUNK)                      // 8 rows per thread
#define ROWS_PER_BLOCK (THREADS * RPT)            // 2048

typedef float v4f __attribute__((ext_vector_type(4)));

// Extract float (idx = compile-time const after unroll) from a float4[KPOT] chunk.
#define GEL(c, idx) ((idx) % 4 == 0 ? gv[c][(idx) / 4].x : \
                     (idx) % 4 == 1 ? gv[c][(idx) / 4].y : \
                     (idx) % 4 == 2 ? gv[c][(idx) / 4].z : gv[c][(idx) / 4].w)

// Deep-MLP streaming design — no LDS, no barrier, 18 loads in flight per wave.
// Each thread owns 8 consecutive-ish rows as TWO 4-row chunks; both chunks'
// loads (2x9 dwordx4) are issued before any compute, so each wave presents
// ~18 KB of outstanding reads to the memory system. grid = 2048 blocks =
// exactly 8 blocks/CU: a single resident generation, no relaunch churn.
__global__ __launch_bounds__(THREADS) void lightsb_kernel(
    const float* __restrict__ x,
    const float* __restrict__ r,
    const float* __restrict__ log_S,
    const float* __restrict__ log_alpha,
    const float* __restrict__ gumbel,
    const float* __restrict__ noise,
    float* __restrict__ out,
    int n_rows)
{
    const int t = threadIdx.x;
    const long long blockRow0 = (long long)blockIdx.x * ROWS_PER_BLOCK;

    float S0[KPOT], S1[KPOT], r0[KPOT], r1[KPOT], la[KPOT];

    if (blockRow0 + ROWS_PER_BLOCK <= n_rows) {
        // ---- issue ALL global loads up-front (18 x dwordx4 per thread) ----
        float4 xv[NCHUNK][2], nv[NCHUNK][2], gv[NCHUNK][KPOT];
#pragma unroll
        for (int c = 0; c < NCHUNK; ++c) {
            const long long row0 = blockRow0 + (long long)c * (THREADS * CHUNK);
            const float4* x4 = reinterpret_cast<const float4*>(x) + row0 / 2;
            const float4* n4 = reinterpret_cast<const float4*>(noise) + row0 / 2;
            const float4* g4 = reinterpret_cast<const float4*>(gumbel) + row0 * KPOT / 4;
            xv[c][0] = x4[2 * t];          // rows 4t, 4t+1 of this chunk
            xv[c][1] = x4[2 * t + 1];      // rows 4t+2, 4t+3
            nv[c][0] = n4[2 * t];
            nv[c][1] = n4[2 * t + 1];
#pragma unroll
            for (int j = 0; j < KPOT; ++j)
                gv[c][j] = g4[KPOT * t + j];   // 20 consecutive floats
        }

        // ---- per-k constants (uniform, cached) while loads are in flight ----
#pragma unroll
        for (int k = 0; k < KPOT; ++k) {
            S0[k] = expf(log_S[2 * k + 0]);
            S1[k] = expf(log_S[2 * k + 1]);
            r0[k] = r[2 * k + 0];
            r1[k] = r[2 * k + 1];
            la[k] = log_alpha[k];
        }

#pragma unroll
        for (int c = 0; c < NCHUNK; ++c) {
            float ov[2 * CHUNK];
#pragma unroll
            for (int i = 0; i < CHUNK; ++i) {
                const float xx0 = (i == 0) ? xv[c][0].x : (i == 1) ? xv[c][0].z
                                : (i == 2) ? xv[c][1].x : xv[c][1].z;
                const float xx1 = (i == 0) ? xv[c][0].y : (i == 1) ? xv[c][0].w
                                : (i == 2) ? xv[c][1].y : xv[c][1].w;
                const float nn0 = (i == 0) ? nv[c][0].x : (i == 1) ? nv[c][0].z
                                : (i == 2) ? nv[c][1].x : nv[c][1].z;
                const float nn1 = (i == 0) ? nv[c][0].y : (i == 1) ? nv[c][0].w
                                : (i == 2) ? nv[c][1].y : nv[c][1].w;

                const float u0 = 0.5f * xx0 * xx0;
                const float u1 = 0.5f * xx1 * xx1;

                // logits_k = S0k*u0 + S1k*u1 + r0k*x0 + r1k*x1 + la_k + g_k
                float best = fmaf(S0[0], u0, fmaf(S1[0], u1,
                             fmaf(r0[0], xx0, fmaf(r1[0], xx1, la[0]))))
                             + GEL(c, KPOT * i + 0);
                float bS0 = S0[0], bS1 = S1[0];
                float br0 = r0[0], br1 = r1[0];
#pragma unroll
                for (int k = 1; k < KPOT; ++k) {
                    float s = fmaf(S0[k], u0, fmaf(S1[k], u1,
                              fmaf(r0[k], xx0, fmaf(r1[k], xx1, la[k]))))
                              + GEL(c, KPOT * i + k);
                    bool cc = s > best;     // strict > keeps first max (jnp.argmax)
                    best = cc ? s : best;
                    bS0 = cc ? S0[k] : bS0;
                    bS1 = cc ? S1[k] : bS1;
                    br0 = cc ? r0[k] : br0;
                    br1 = cc ? r1[k] : br1;
                }
                const float bq0 = sqrtf(bS0);   // EPS = 1.0; sqrt only for winner
                const float bq1 = sqrtf(bS1);
                ov[2 * i + 0] = fmaf(bS0, xx0, fmaf(bq0, nn0, br0));
                ov[2 * i + 1] = fmaf(bS1, xx1, fmaf(bq1, nn1, br1));
            }
            const long long row0 = blockRow0 + (long long)c * (THREADS * CHUNK);
            v4f* o4 = reinterpret_cast<v4f*>(out) + row0 / 2;
            v4f o0 = { ov[0], ov[1], ov[2], ov[3] };
            v4f o1 = { ov[4], ov[5], ov[6], ov[7] };
            __builtin_nontemporal_store(o0, o4 + 2 * t);
            __builtin_nontemporal_store(o1, o4 + 2 * t + 1);
        }
    } else {
        // ---- scalar fallback for a partial last block (n_rows % 2048 != 0) ----
        float q0[KPOT], q1[KPOT];
#pragma unroll
        for (int k = 0; k < KPOT; ++k) {
            float s0 = expf(log_S[2 * k + 0]);
            float s1 = expf(log_S[2 * k + 1]);
            S0[k] = s0;  S1[k] = s1;
            r0[k] = r[2 * k + 0];  r1[k] = r[2 * k + 1];
            la[k] = log_alpha[k];
            q0[k] = sqrtf(s0);  q1[k] = sqrtf(s1);
        }
        for (long long row = blockRow0 + t; row < n_rows; row += THREADS) {
            float x0 = x[row * 2 + 0];
            float x1 = x[row * 2 + 1];
            float u0 = 0.5f * x0 * x0;
            float u1 = 0.5f * x1 * x1;
            float best = fmaf(S0[0], u0, fmaf(S1[0], u1,
                         fmaf(r0[0], x0, fmaf(r1[0], x1, la[0] + gumbel[row * KPOT + 0]))));
            int bidx = 0;
#pragma unroll
            for (int k = 1; k < KPOT; ++k) {
                float s = fmaf(S0[k], u0, fmaf(S1[k], u1,
                          fmaf(r0[k], x0, fmaf(r1[k], x1, la[k] + gumbel[row * KPOT + k]))));
                if (s > best) { best = s; bidx = k; }
            }
            float n0 = noise[row * 2 + 0];
            float n1 = noise[row * 2 + 1];
            out[row * 2 + 0] = fmaf(S0[bidx], x0, fmaf(q0[bidx], n0, r0[bidx]));
            out[row * 2 + 1] = fmaf(S1[bidx], x1, fmaf(q1[bidx], n1, r1[bidx]));
        }
    }
}

extern "C" void kernel_launch(void* const* d_in, const int* in_sizes, int n_in,
                              void* d_out, int out_size, void* d_ws, size_t ws_size,
                              hipStream_t stream) {
    const float* x         = (const float*)d_in[0];
    const float* r         = (const float*)d_in[1];
    const float* log_S     = (const float*)d_in[2];
    const float* log_alpha = (const float*)d_in[3];
    const float* gumbel    = (const float*)d_in[4];
    const float* noise     = (const float*)d_in[5];
    float* out = (float*)d_out;

    const int n_rows = in_sizes[0] / 2;                      // DIM = 2
    const int grid = (n_rows + ROWS_PER_BLOCK - 1) / ROWS_PER_BLOCK;

    lightsb_kernel<<<grid, THREADS, 0, stream>>>(x, r, log_S, log_alpha,
                                                 gumbel, noise, out, n_rows);
}

// Round 3
// 189.084 us; speedup vs baseline: 1.0712x; 1.0712x over previous
//
#include <hip/hip_runtime.h>
#include <math.h>

#define KPOT 5
#define THREADS 256
#define ROWS_PER_BLOCK 1024                       // grid = 4096 (round-0 geometry)

// LDS tiles (all linear, byte sizes):  x 8 KB | noise 8 KB | gumbel 20 KB = 36 KB
#define XFLOATS (ROWS_PER_BLOCK * 2)              // 2048
#define GFLOATS (ROWS_PER_BLOCK * KPOT)           // 5120

// global -> LDS async DMA, 16 B per lane per call (1024 B per wave-call).
// lptr must be WAVE-UNIFORM; HW writes lane data at lptr + 16*lane.
__device__ __forceinline__ void load_lds16(const float* gptr, float* lptr) {
    __builtin_amdgcn_global_load_lds(
        (const __attribute__((address_space(1))) void*)gptr,
        (__attribute__((address_space(3))) void*)lptr, 16, 0, 0);
}

// Round-0 structure (coalesced tiles, LDS reads, 0 bank conflicts), but ALL
// read streams staged through the global_load_lds DMA queue instead of the
// TCP/VGPR path — testing the per-CU outstanding-miss-capacity theory.
// 9 DMA calls per wave (x:2, noise:2, gumbel:5), one barrier, then compute.
__global__ __launch_bounds__(THREADS) void lightsb_kernel(
    const float* __restrict__ x,
    const float* __restrict__ r,
    const float* __restrict__ log_S,
    const float* __restrict__ log_alpha,
    const float* __restrict__ gumbel,
    const float* __restrict__ noise,
    float* __restrict__ out,
    int n_rows)
{
    __shared__ float xsh[XFLOATS];
    __shared__ float nsh[XFLOATS];
    __shared__ float gsh[GFLOATS];

    const int t = threadIdx.x;
    const long long blockRow0 = (long long)blockIdx.x * ROWS_PER_BLOCK;

    float S0[KPOT], S1[KPOT], r0[KPOT], r1[KPOT], la[KPOT], q0[KPOT], q1[KPOT];

    if (blockRow0 + ROWS_PER_BLOCK <= n_rows) {
        const int w    = t >> 6;          // wave id 0..3
        const int lane = t & 63;

        const float* xg = x      + blockRow0 * 2;       // 8192 B tile
        const float* ng = noise  + blockRow0 * 2;       // 8192 B tile
        const float* gg = gumbel + blockRow0 * KPOT;    // 20480 B tile

        // ---- issue all DMA staging (9 wave-calls each of 1024 B) ----
#pragma unroll
        for (int j = 0; j < 2; ++j) {                    // x, noise: 8 chunks each
            const int c = w + 4 * j;                     // chunk of 256 floats
            load_lds16(xg + c * 256 + lane * 4, &xsh[c * 256]);
            load_lds16(ng + c * 256 + lane * 4, &nsh[c * 256]);
        }
#pragma unroll
        for (int j = 0; j < 5; ++j) {                    // gumbel: 20 chunks
            const int c = w + 4 * j;
            load_lds16(gg + c * 256 + lane * 4, &gsh[c * 256]);
        }

        // ---- per-k constants (uniform, cached) while DMA is in flight ----
#pragma unroll
        for (int k = 0; k < KPOT; ++k) {
            float s0 = expf(log_S[2 * k + 0]);
            float s1 = expf(log_S[2 * k + 1]);
            S0[k] = s0;  S1[k] = s1;
            r0[k] = r[2 * k + 0];  r1[k] = r[2 * k + 1];
            la[k] = log_alpha[k];
            q0[k] = sqrtf(s0);  q1[k] = sqrtf(s1);       // EPS = 1.0
        }

        __syncthreads();    // compiler emits s_waitcnt vmcnt(0) before s_barrier

        const float4* xs4 = reinterpret_cast<const float4*>(xsh);
        const float4* ns4 = reinterpret_cast<const float4*>(nsh);
        float4* o4 = reinterpret_cast<float4*>(out) + blockRow0 / 2;

#pragma unroll
        for (int p = 0; p < 2; ++p) {
            const float4 xv = xs4[p * 256 + t];          // rows p*512+2t, +1
            const float4 nv = ns4[p * 256 + t];
            const int lr0 = p * 512 + 2 * t;
            const float* g0 = &gsh[lr0 * KPOT];          // 10 consecutive floats
            float ov[4];

#pragma unroll
            for (int h = 0; h < 2; ++h) {                // two rows in this float4
                const float xx0 = (h == 0) ? xv.x : xv.z;
                const float xx1 = (h == 0) ? xv.y : xv.w;
                const float nn0 = (h == 0) ? nv.x : nv.z;
                const float nn1 = (h == 0) ? nv.y : nv.w;
                const float* g = g0 + h * KPOT;

                const float u0 = 0.5f * xx0 * xx0;
                const float u1 = 0.5f * xx1 * xx1;

                float best = fmaf(S0[0], u0, fmaf(S1[0], u1,
                             fmaf(r0[0], xx0, fmaf(r1[0], xx1, la[0] + g[0]))));
                float bS0 = S0[0], bS1 = S1[0];
                float br0 = r0[0], br1 = r1[0];
                float bq0 = q0[0], bq1 = q1[0];
#pragma unroll
                for (int k = 1; k < KPOT; ++k) {
                    float s = fmaf(S0[k], u0, fmaf(S1[k], u1,
                              fmaf(r0[k], xx0, fmaf(r1[k], xx1, la[k] + g[k]))));
                    bool c = s > best;     // strict > keeps first max (jnp.argmax)
                    best = c ? s : best;
                    bS0 = c ? S0[k] : bS0;
                    bS1 = c ? S1[k] : bS1;
                    br0 = c ? r0[k] : br0;
                    br1 = c ? r1[k] : br1;
                    bq0 = c ? q0[k] : bq0;
                    bq1 = c ? q1[k] : bq1;
                }
                ov[2 * h + 0] = fmaf(bS0, xx0, fmaf(bq0, nn0, br0));
                ov[2 * h + 1] = fmaf(bS1, xx1, fmaf(bq1, nn1, br1));
            }
            o4[p * 256 + t] = make_float4(ov[0], ov[1], ov[2], ov[3]);
        }
    } else {
        // ---- scalar fallback for a partial last block (n_rows % 1024 != 0) ----
#pragma unroll
        for (int k = 0; k < KPOT; ++k) {
            float s0 = expf(log_S[2 * k + 0]);
            float s1 = expf(log_S[2 * k + 1]);
            S0[k] = s0;  S1[k] = s1;
            r0[k] = r[2 * k + 0];  r1[k] = r[2 * k + 1];
            la[k] = log_alpha[k];
            q0[k] = sqrtf(s0);  q1[k] = sqrtf(s1);
        }
        for (long long row = blockRow0 + t; row < n_rows; row += THREADS) {
            float x0 = x[row * 2 + 0];
            float x1 = x[row * 2 + 1];
            float u0 = 0.5f * x0 * x0;
            float u1 = 0.5f * x1 * x1;
            float best = fmaf(S0[0], u0, fmaf(S1[0], u1,
                         fmaf(r0[0], x0, fmaf(r1[0], x1, la[0] + gumbel[row * KPOT + 0]))));
            int bidx = 0;
#pragma unroll
            for (int k = 1; k < KPOT; ++k) {
                float s = fmaf(S0[k], u0, fmaf(S1[k], u1,
                          fmaf(r0[k], x0, fmaf(r1[k], x1, la[k] + gumbel[row * KPOT + k]))));
                if (s > best) { best = s; bidx = k; }
            }
            float n0 = noise[row * 2 + 0];
            float n1 = noise[row * 2 + 1];
            out[row * 2 + 0] = fmaf(S0[bidx], x0, fmaf(q0[bidx], n0, r0[bidx]));
            out[row * 2 + 1] = fmaf(S1[bidx], x1, fmaf(q1[bidx], n1, r1[bidx]));
        }
    }
}

extern "C" void kernel_launch(void* const* d_in, const int* in_sizes, int n_in,
                              void* d_out, int out_size, void* d_ws, size_t ws_size,
                              hipStream_t stream) {
    const float* x         = (const float*)d_in[0];
    const float* r         = (const float*)d_in[1];
    const float* log_S     = (const float*)d_in[2];
    const float* log_alpha = (const float*)d_in[3];
    const float* gumbel    = (const float*)d_in[4];
    const float* noise     = (const float*)d_in[5];
    float* out = (float*)d_out;

    const int n_rows = in_sizes[0] / 2;                      // DIM = 2
    const int grid = (n_rows + ROWS_PER_BLOCK - 1) / ROWS_PER_BLOCK;

    lightsb_kernel<<<grid, THREADS, 0, stream>>>(x, r, log_S, log_alpha,
                                                 gumbel, noise, out, n_rows);
}